// Round 12
// baseline (546.557 us; speedup 1.0000x reference)
//
#include <hip/hip_runtime.h>

#define NPTS 16384
#define NB   8
#define NM   2048
#define NC   128
#define EPSF 1e-8f

#define TQ   16                     // threads per query
#define QPB  16                     // queries per 256-thread block
#define GX   96                     // 768 blocks = 3/CU (48KB LDS) in ONE residency round;
                                    // window loop covers segN (~2090) with 1-2 windows/block

#define GRD   16
#define NCELL (GRD * GRD * GRD)
#define H     0.5f
#define INVH  2.0f
#define ORG   (-4.0f)

// lexicographic (d, idx) top-3 insert — order-invariant, exact tie-break == top_k
#define MERGE_DI(ed, ei) do {                                           \
    const bool _b2 = ((ed) < D2) || (((ed) == D2) && ((ei) < I2));      \
    const bool _b1 = ((ed) < D1) || (((ed) == D1) && ((ei) < I1));      \
    const bool _b0 = ((ed) < D0) || (((ed) == D0) && ((ei) < I0));      \
    D2 = _b1 ? D1 : (_b2 ? (ed) : D2);                                  \
    I2 = _b1 ? I1 : (_b2 ? (ei) : I2);                                  \
    D1 = _b0 ? D0 : (_b1 ? (ed) : D1);                                  \
    I1 = _b0 ? I0 : (_b1 ? (ei) : I1);                                  \
    D0 = _b0 ? (ed) : D0;                                               \
    I0 = _b0 ? (ei) : I0;                                               \
} while (0)

#define DIST_RN(dd, qx, qy, qz, px, py, pz) do {                        \
    const float _dx = __fsub_rn((qx), (px));                            \
    const float _dy = __fsub_rn((qy), (py));                            \
    const float _dz = __fsub_rn((qz), (pz));                            \
    (dd) = __fadd_rn(__fadd_rn(__fmul_rn(_dx, _dx), __fmul_rn(_dy, _dy)), \
                     __fmul_rn(_dz, _dz));                              \
} while (0)

__device__ __forceinline__ int cellOf(float v) {
    int c = (int)floorf(__fmul_rn(__fsub_rn(v, ORG), INVH));
    return c < 0 ? 0 : (c > GRD - 1 ? GRD - 1 : c);
}

// ONE dispatch. Per block: scan binds (rank window) -> bin batch's 2048 points into a
// 16^3 LDS grid -> per query: ring search with exact termination bound -> gather.
__global__ __launch_bounds__(256, 3) void fused(const float* __restrict__ unknown,
                                                const float* __restrict__ known,
                                                const int*   __restrict__ binds,
                                                const float* __restrict__ feats,
                                                float* __restrict__ out) {
    __shared__ int   cellA[NCELL];          // 16 KB: counts -> starts -> ends
    __shared__ float spx[NM], spy[NM], spz[NM];   // 24 KB, cell-sorted coords
    __shared__ unsigned short sid[NM];      // 4 KB, cell-sorted original index
    __shared__ int qlist[QPB];
    __shared__ int wsum[4];
    __shared__ int wsum2[4];

    const int tid  = threadIdx.x;
    const int b    = blockIdx.y;
    const int x    = blockIdx.x;
    const int lane = tid & 63;
    const int wave = tid >> 6;

    // ---- scan binds: rank prefix (identical to R11) ----
    const int4* b4 = (const int4*)binds;
    int myCnt = 0;
#pragma unroll
    for (int r = 0; r < 16; ++r) {
        const int4 v = b4[tid * 16 + r];
        myCnt += (v.x == b) + (v.y == b) + (v.z == b) + (v.w == b);
    }
    int incv = myCnt;
#pragma unroll
    for (int off = 1; off <= 32; off <<= 1) {
        const int n = __shfl_up(incv, off);
        if (lane >= off) incv += n;
    }
    if (lane == 63) wsum[wave] = incv;
    __syncthreads();
    int wbase = 0;
    for (int w = 0; w < wave; ++w) wbase += wsum[w];
    const int exPre = wbase + incv - myCnt;
    const int segN  = wsum[0] + wsum[1] + wsum[2] + wsum[3];

    if (x * QPB >= segN) return;           // block-uniform early exit

    // ---- bin batch b's points into the LDS grid ----
    for (int c = tid; c < NCELL; c += 256) cellA[c] = 0;
    __syncthreads();

    float px[8], py[8], pz[8];
    int   pc[8];
    {
        const float* kb = known + (size_t)b * NM * 3;
#pragma unroll
        for (int k = 0; k < 8; ++k) {
            const int j = tid * 8 + k;
            px[k] = kb[j * 3 + 0];
            py[k] = kb[j * 3 + 1];
            pz[k] = kb[j * 3 + 2];
            pc[k] = (cellOf(pz[k]) * GRD + cellOf(py[k])) * GRD + cellOf(px[k]);
            atomicAdd(&cellA[pc[k]], 1);
        }
    }
    __syncthreads();

    {   // exclusive prefix over 4096 counts (16 cells/thread)
        int cnt[16];
#pragma unroll
        for (int k = 0; k < 16; ++k) cnt[k] = cellA[tid * 16 + k];
        int tsum = 0;
#pragma unroll
        for (int k = 0; k < 16; ++k) tsum += cnt[k];
        int winc = tsum;
#pragma unroll
        for (int off = 1; off <= 32; off <<= 1) {
            const int n = __shfl_up(winc, off);
            if (lane >= off) winc += n;
        }
        if (lane == 63) wsum2[wave] = winc;
        __syncthreads();
        int wb2 = 0;
        for (int w = 0; w < wave; ++w) wb2 += wsum2[w];
        int run = wb2 + winc - tsum;
#pragma unroll
        for (int k = 0; k < 16; ++k) { cellA[tid * 16 + k] = run; run += cnt[k]; }
    }
    __syncthreads();

    {   // scatter (cursor = starts -> becomes ends)
#pragma unroll
        for (int k = 0; k < 8; ++k) {
            const int pos = atomicAdd(&cellA[pc[k]], 1);
            spx[pos] = px[k];
            spy[pos] = py[k];
            spz[pos] = pz[k];
            sid[pos] = (unsigned short)(tid * 8 + k);
        }
    }
    __syncthreads();   // cellA[c] = end(c); start(c) = c ? cellA[c-1] : 0

    const int qi = tid >> 4;
    const int t  = tid & 15;

    for (int w0 = x * QPB; w0 < segN; w0 += GX * QPB) {
        __syncthreads();       // previous window's qlist reads done
        if (exPre < w0 + QPB && exPre + myCnt > w0) {
            int rank = exPre;
#pragma unroll
            for (int r = 0; r < 16; ++r) {
                const int4 v = b4[tid * 16 + r];
                const int base = tid * 64 + r * 4;
                if (v.x == b) { if (rank >= w0 && rank < w0 + QPB) qlist[rank - w0] = base + 0; ++rank; }
                if (v.y == b) { if (rank >= w0 && rank < w0 + QPB) qlist[rank - w0] = base + 1; ++rank; }
                if (v.z == b) { if (rank >= w0 && rank < w0 + QPB) qlist[rank - w0] = base + 2; ++rank; }
                if (v.w == b) { if (rank >= w0 && rank < w0 + QPB) qlist[rank - w0] = base + 3; ++rank; }
            }
        }
        __syncthreads();

        const int valid = (segN - w0 < QPB) ? (segN - w0) : QPB;
        const int kq    = (qi < valid) ? qi : 0;   // duplicate -> identical bytes, benign
        const int p     = qlist[kq];
        const float ux = unknown[p * 3 + 0];
        const float uy = unknown[p * 3 + 1];
        const float uz = unknown[p * 3 + 2];

        const int icx = cellOf(ux), icy = cellOf(uy), icz = cellOf(uz);

        float D0 = __builtin_inff(), D1 = __builtin_inff(), D2 = __builtin_inff();
        int   I0 = NM, I1 = NM, I2 = NM;

        // pass 1: rings 0..1 (27 cells), thread-strided
        for (int s = t; s < 27; s += TQ) {
            const int dx = s % 3 - 1, dy = (s / 3) % 3 - 1, dz = s / 9 - 1;
            const int cx = icx + dx, cy = icy + dy, cz = icz + dz;
            if (cx < 0 || cx >= GRD || cy < 0 || cy >= GRD || cz < 0 || cz >= GRD) continue;
            const int cid = (cz * GRD + cy) * GRD + cx;
            const int lo  = cid ? cellA[cid - 1] : 0;
            const int hi  = cellA[cid];
            for (int k2 = lo; k2 < hi; ++k2) {
                float d; DIST_RN(d, ux, uy, uz, spx[k2], spy[k2], spz[k2]);
                const int jj = (int)sid[k2];
                MERGE_DI(d, jj);
            }
        }

        // expanding rings with exact termination bound
        int c = 1;
        while (true) {
            // dbound: min distance from q to the unexamined region (edge faces -> inf)
            float db = __builtin_inff();
            if (icx - c > 0)       db = fminf(db, __fsub_rn(ux, ORG + (icx - c) * H));
            if (icx + c < GRD - 1) db = fminf(db, __fsub_rn(ORG + (icx + c + 1) * H, ux));
            if (icy - c > 0)       db = fminf(db, __fsub_rn(uy, ORG + (icy - c) * H));
            if (icy + c < GRD - 1) db = fminf(db, __fsub_rn(ORG + (icy + c + 1) * H, uy));
            if (icz - c > 0)       db = fminf(db, __fsub_rn(uz, ORG + (icz - c) * H));
            if (icz + c < GRD - 1) db = fminf(db, __fsub_rn(ORG + (icz + c + 1) * H, uz));
            // group 3rd-best <= min over threads of per-thread D2 (each holds 3 candidates)
            float m2 = D2;
#pragma unroll
            for (int off = 1; off < TQ; off <<= 1) m2 = fminf(m2, __shfl_xor(m2, off));
            if (m2 < db * db || c >= GRD) break;

            ++c;
            int kk = 0;
            for (int dz = -c; dz <= c; ++dz)
                for (int dy = -c; dy <= c; ++dy)
                    for (int dx = -c; dx <= c; ++dx) {
                        const int ax = dx < 0 ? -dx : dx;
                        const int ay = dy < 0 ? -dy : dy;
                        const int az = dz < 0 ? -dz : dz;
                        const int ch = ax > ay ? (ax > az ? ax : az) : (ay > az ? ay : az);
                        if (ch != c) continue;            // interior already examined
                        if ((kk++ & (TQ - 1)) != t) continue;
                        const int cx = icx + dx, cy = icy + dy, cz = icz + dz;
                        if (cx < 0 || cx >= GRD || cy < 0 || cy >= GRD || cz < 0 || cz >= GRD) continue;
                        const int cid = (cz * GRD + cy) * GRD + cx;
                        const int lo  = cid ? cellA[cid - 1] : 0;
                        const int hi  = cellA[cid];
                        for (int k2 = lo; k2 < hi; ++k2) {
                            float d; DIST_RN(d, ux, uy, uz, spx[k2], spy[k2], spz[k2]);
                            const int jj = (int)sid[k2];
                            MERGE_DI(d, jj);
                        }
                    }
        }

        // merge 16 partial top-3 lists (shfl_down tree; valid at group lane 0), broadcast
#pragma unroll
        for (int off = 8; off >= 1; off >>= 1) {
            const float e0d = __shfl_down(D0, off);
            const float e1d = __shfl_down(D1, off);
            const float e2d = __shfl_down(D2, off);
            const int   e0i = __shfl_down(I0, off);
            const int   e1i = __shfl_down(I1, off);
            const int   e2i = __shfl_down(I2, off);
            MERGE_DI(e0d, e0i);
            MERGE_DI(e1d, e1i);
            MERGE_DI(e2d, e2i);
        }
        const int src = lane & ~15;
        D0 = __shfl(D0, src); D1 = __shfl(D1, src); D2 = __shfl(D2, src);
        I0 = __shfl(I0, src); I1 = __shfl(I1, src); I2 = __shfl(I2, src);

        const float t0 = 1.0f / (sqrtf(D0) + EPSF);
        const float t1 = 1.0f / (sqrtf(D1) + EPSF);
        const float t2 = 1.0f / (sqrtf(D2) + EPSF);
        const float s  = t0 + t1 + t2;
        const float w0w = t0 / s, w1w = t1 / s, w2w = t2 / s;

        const float* fb = feats + (size_t)b * NC * NM;
#pragma unroll
        for (int k = 0; k < 8; ++k) {
            const int cch = t + (k << 4);
            const float* fc = fb + (size_t)cch * NM;
            out[(size_t)p * NC + cch] = w0w * fc[I0] + w1w * fc[I1] + w2w * fc[I2];
        }
    }
}

extern "C" void kernel_launch(void* const* d_in, const int* in_sizes, int n_in,
                              void* d_out, int out_size, void* d_ws, size_t ws_size,
                              hipStream_t stream) {
    const float* unknown = (const float*)d_in[0];   // (n, 3)
    const float* known   = (const float*)d_in[1];   // (B, m, 3)
    const int*   binds   = (const int*)d_in[2];     // (n,)
    const float* feats   = (const float*)d_in[3];   // (B, C, m)
    float*       out     = (float*)d_out;           // (n, C, 1)

    fused<<<dim3(GX, NB), 256, 0, stream>>>(unknown, known, binds, feats, out);
}

// Round 13
// 153.054 us; speedup vs baseline: 3.5710x; 3.5710x over previous
//
#include <hip/hip_runtime.h>

#define NPTS 16384
#define NB   8
#define NC   128
#define NM   2048
#define EPSF 1e-8f

#define QPB  16                     // queries per 256-thread block (4 waves x 4 rounds)
#define GX   160                    // blocks per batch: 2560 slots >> segN(~2100)

#define NBUK 32
#define W    0.25f
#define INVW 4.0f
#define ORG  (-4.0f)

// lexicographic (d, idx) top-3 insert — order-invariant, exact top_k tie-break
#define MERGE_DI(ed, ei) do {                                           \
    const bool _b2 = ((ed) < D2) || (((ed) == D2) && ((ei) < I2));      \
    const bool _b1 = ((ed) < D1) || (((ed) == D1) && ((ei) < I1));      \
    const bool _b0 = ((ed) < D0) || (((ed) == D0) && ((ei) < I0));      \
    D2 = _b1 ? D1 : (_b2 ? (ed) : D2);                                  \
    I2 = _b1 ? I1 : (_b2 ? (ei) : I2);                                  \
    D1 = _b0 ? D0 : (_b1 ? (ed) : D1);                                  \
    I1 = _b0 ? I0 : (_b1 ? (ei) : I1);                                  \
    D0 = _b0 ? (ed) : D0;                                               \
    I0 = _b0 ? (ei) : I0;                                               \
} while (0)

// process one bucket: contiguous 64-wide chunks, lane-coalesced LDS reads
#define PROC_BUCKET(bk) do {                                            \
    const int _lo = bstart[bk], _hi = bend[bk];                         \
    for (int _k0 = _lo; _k0 < _hi; _k0 += 64) {                         \
        const int  _k2 = _k0 + lane;                                    \
        const bool _a  = _k2 < _hi;                                     \
        const int  _ka = _a ? _k2 : _lo;                                \
        const float _dx = __fsub_rn(ux, sx[_ka]);                       \
        const float _dy = __fsub_rn(uy, sy[_ka]);                       \
        const float _dz = __fsub_rn(uz, sz[_ka]);                       \
        float _d = __fadd_rn(__fadd_rn(__fmul_rn(_dx, _dx),             \
                                       __fmul_rn(_dy, _dy)),            \
                             __fmul_rn(_dz, _dz));                      \
        _d = _a ? _d : __builtin_inff();                                \
        const int _jj = _a ? (int)sid[_ka] : NM;                        \
        MERGE_DI(_d, _jj);                                              \
    }                                                                   \
} while (0)

__device__ __forceinline__ int bukOf(float v) {
    int c = (int)floorf(__fmul_rn(__fsub_rn(v, ORG), INVW));
    return c < 0 ? 0 : (c > NBUK - 1 ? NBUK - 1 : c);
}

// ONE dispatch. Per block: rank-scan binds; bin batch's points into 32 x-buckets in LDS
// (cell-sorted SoA); one query per WAVE with exact-bound expanding bucket walk; gather.
__global__ __launch_bounds__(256, 4) void fused(const float* __restrict__ unknown,
                                                const float* __restrict__ known,
                                                const int*   __restrict__ binds,
                                                const float* __restrict__ feats,
                                                float* __restrict__ out) {
    __shared__ float sx[NM], sy[NM], sz[NM];     // 24 KB cell-sorted coords
    __shared__ unsigned short sid[NM];           // 4 KB original index
    __shared__ int bcnt[NBUK], bstart[NBUK], bend[NBUK], bcur[NBUK];
    __shared__ int qlist[QPB];
    __shared__ int wsum[4];

    const int tid  = threadIdx.x;
    const int b    = blockIdx.y;
    const int x    = blockIdx.x;
    const int lane = tid & 63;
    const int wave = tid >> 6;

    // ---- scan binds: per-thread count of batch-b points, 256-thread exclusive prefix ----
    const int4* b4 = (const int4*)binds;   // thread t owns binds[t*64 .. t*64+63]
    int myCnt = 0;
#pragma unroll
    for (int r = 0; r < 16; ++r) {
        const int4 v = b4[tid * 16 + r];
        myCnt += (v.x == b) + (v.y == b) + (v.z == b) + (v.w == b);
    }
    int inc = myCnt;
#pragma unroll
    for (int off = 1; off <= 32; off <<= 1) {
        const int n = __shfl_up(inc, off);
        if (lane >= off) inc += n;
    }
    if (lane == 63) wsum[wave] = inc;
    if (tid < NBUK) bcnt[tid] = 0;
    __syncthreads();
    int wbase = 0;
    for (int w = 0; w < wave; ++w) wbase += wsum[w];
    const int exPre = wbase + inc - myCnt;
    const int segN  = wsum[0] + wsum[1] + wsum[2] + wsum[3];

    if (x * QPB >= segN) return;           // block-uniform early exit

    // ---- bin batch b's 2048 points into 32 x-buckets ----
    float px[8], py[8], pz[8];
    int   pb[8];
    {
        const float* kb = known + (size_t)b * NM * 3;
#pragma unroll
        for (int k = 0; k < 8; ++k) {
            const int j = tid * 8 + k;
            px[k] = kb[j * 3 + 0];
            py[k] = kb[j * 3 + 1];
            pz[k] = kb[j * 3 + 2];
            pb[k] = bukOf(px[k]);
            atomicAdd(&bcnt[pb[k]], 1);
        }
    }
    __syncthreads();
    if (wave == 0) {                       // 32-wide prefix by wave 0
        const int c = (lane < NBUK) ? bcnt[lane] : 0;
        int ip = c;
#pragma unroll
        for (int off = 1; off < NBUK; off <<= 1) {
            const int n = __shfl_up(ip, off);
            if (lane >= off) ip += n;
        }
        if (lane < NBUK) { bend[lane] = ip; bstart[lane] = ip - c; bcur[lane] = ip - c; }
    }
    __syncthreads();
    {
#pragma unroll
        for (int k = 0; k < 8; ++k) {
            const int pos = atomicAdd(&bcur[pb[k]], 1);
            sx[pos] = px[k];
            sy[pos] = py[k];
            sz[pos] = pz[k];
            sid[pos] = (unsigned short)(tid * 8 + k);
        }
    }
    __syncthreads();

    // ---- window loop (one window since GX*QPB >= segN; safety net otherwise) ----
    for (int w0 = x * QPB; w0 < segN; w0 += GX * QPB) {
        __syncthreads();       // previous window's qlist reads done
        if (exPre < w0 + QPB && exPre + myCnt > w0) {
            int rank = exPre;
#pragma unroll
            for (int r = 0; r < 16; ++r) {
                const int4 v = b4[tid * 16 + r];
                const int base = tid * 64 + r * 4;
                if (v.x == b) { if (rank >= w0 && rank < w0 + QPB) qlist[rank - w0] = base + 0; ++rank; }
                if (v.y == b) { if (rank >= w0 && rank < w0 + QPB) qlist[rank - w0] = base + 1; ++rank; }
                if (v.z == b) { if (rank >= w0 && rank < w0 + QPB) qlist[rank - w0] = base + 2; ++rank; }
                if (v.w == b) { if (rank >= w0 && rank < w0 + QPB) qlist[rank - w0] = base + 3; ++rank; }
            }
        }
        __syncthreads();

        const int valid = (segN - w0 < QPB) ? (segN - w0) : QPB;

        // 4 rounds x 4 waves: one query per wave, fully wave-uniform bucket walk
#pragma unroll
        for (int rr = 0; rr < 4; ++rr) {
            const int qidx = rr * 4 + wave;
            const int kq   = (qidx < valid) ? qidx : 0;   // duplicate -> identical bytes
            const int p    = qlist[kq];
            const float ux = unknown[p * 3 + 0];
            const float uy = unknown[p * 3 + 1];
            const float uz = unknown[p * 3 + 2];
            const int ib   = bukOf(ux);

            float D0 = __builtin_inff(), D1 = __builtin_inff(), D2 = __builtin_inff();
            int   I0 = NM, I1 = NM, I2 = NM;

            int s = 0;
            while (true) {
                const int bl = ib - s, br = ib + s;
                if (bl >= 0) PROC_BUCKET(bl);
                if (s > 0 && br < NBUK) PROC_BUCKET(br);

                const bool hasL = (ib - s) > 0;
                const bool hasR = (ib + s) < NBUK - 1;
                if (!hasL && !hasR) break;                // everything examined
                float db = __builtin_inff();
                if (hasL) db = fminf(db, __fsub_rn(ux, ORG + (float)(ib - s) * W));
                if (hasR) db = fminf(db, __fsub_rn(ORG + (float)(ib + s + 1) * W, ux));
                // wave bound on true 3rd-best: min over lanes of per-lane D2
                float m2 = D2;
#pragma unroll
                for (int off = 32; off >= 1; off >>= 1) m2 = fminf(m2, __shfl_xor(m2, off));
                if (m2 < __fmul_rn(db, db)) break;        // strict: no tie can cross db
                ++s;
            }

            // full 64-lane top-3 tree merge (disjoint partners; valid at lane 0)
#pragma unroll
            for (int off = 32; off >= 1; off >>= 1) {
                const float e0d = __shfl_down(D0, off);
                const float e1d = __shfl_down(D1, off);
                const float e2d = __shfl_down(D2, off);
                const int   e0i = __shfl_down(I0, off);
                const int   e1i = __shfl_down(I1, off);
                const int   e2i = __shfl_down(I2, off);
                MERGE_DI(e0d, e0i);
                MERGE_DI(e1d, e1i);
                MERGE_DI(e2d, e2i);
            }
            D0 = __shfl(D0, 0); D1 = __shfl(D1, 0); D2 = __shfl(D2, 0);
            I0 = __shfl(I0, 0); I1 = __shfl(I1, 0); I2 = __shfl(I2, 0);

            const float t0 = 1.0f / (sqrtf(D0) + EPSF);
            const float t1 = 1.0f / (sqrtf(D1) + EPSF);
            const float t2 = 1.0f / (sqrtf(D2) + EPSF);
            const float sw = t0 + t1 + t2;
            const float w0w = t0 / sw, w1w = t1 / sw, w2w = t2 / sw;

            // gather from raw (B,C,m); wave covers 128 channels as lane, lane+64
            const float* fb = feats + (size_t)b * NC * NM;
#pragma unroll
            for (int k = 0; k < 2; ++k) {
                const int c = lane + (k << 6);
                const float* fc = fb + (size_t)c * NM;
                out[(size_t)p * NC + c] = w0w * fc[I0] + w1w * fc[I1] + w2w * fc[I2];
            }
        }
    }
}

extern "C" void kernel_launch(void* const* d_in, const int* in_sizes, int n_in,
                              void* d_out, int out_size, void* d_ws, size_t ws_size,
                              hipStream_t stream) {
    const float* unknown = (const float*)d_in[0];   // (n, 3)
    const float* known   = (const float*)d_in[1];   // (B, m, 3)
    const int*   binds   = (const int*)d_in[2];     // (n,)
    const float* feats   = (const float*)d_in[3];   // (B, C, m)
    float*       out     = (float*)d_out;           // (n, C, 1)

    fused<<<dim3(GX, NB), 256, 0, stream>>>(unknown, known, binds, feats, out);
}

// Round 14
// 124.244 us; speedup vs baseline: 4.3991x; 1.2319x over previous
//
#include <hip/hip_runtime.h>

#define NPTS 16384
#define NB   8
#define NM   2048
#define NC   128
#define EPSF 1e-8f

#define TQ   32                     // threads per query
#define QPB  8                      // queries per 256-thread block
#define GX   280                    // 2240 slots >= max segN (~2195 worst-case); ~2096 live
                                    // blocks = 8.2/CU -> 6 resident (LDS-capped) = 24 waves/CU

// Sorted top-3 insert via min/med3 + 5 cndmask for indices (strict '<' keeps earliest j;
// per-thread j strictly increases). Verified R11.
#define MERGE3(d, j) do {                                       \
    const bool _b0 = (d) < D0;                                  \
    const bool _b1 = (d) < D1;                                  \
    const bool _b2 = (d) < D2;                                  \
    const float _n0 = fminf((d), D0);                           \
    const float _n1 = __builtin_amdgcn_fmed3f(D0, D1, (d));     \
    const float _n2 = __builtin_amdgcn_fmed3f(D1, D2, (d));     \
    I2 = _b1 ? I1 : (_b2 ? (j) : I2);                           \
    I1 = _b0 ? I0 : (_b1 ? (j) : I1);                           \
    I0 = _b0 ? (j) : I0;                                        \
    D0 = _n0; D1 = _n1; D2 = _n2;                               \
} while (0)

// Cross-thread merge element: full lexicographic (d, idx) compare (once per query)
#define MERGE_DI(ed, ei) do {                                           \
    const bool _b2 = ((ed) < D2) || (((ed) == D2) && ((ei) < I2));      \
    const bool _b1 = ((ed) < D1) || (((ed) == D1) && ((ei) < I1));      \
    const bool _b0 = ((ed) < D0) || (((ed) == D0) && ((ei) < I0));      \
    D2 = _b1 ? D1 : (_b2 ? (ed) : D2);                                  \
    I2 = _b1 ? I1 : (_b2 ? (ei) : I2);                                  \
    D1 = _b0 ? D0 : (_b1 ? (ed) : D1);                                  \
    I1 = _b0 ? I0 : (_b1 ? (ei) : I1);                                  \
    D0 = _b0 ? (ed) : D0;                                               \
    I0 = _b0 ? (ei) : I0;                                               \
} while (0)

// ONE dispatch, no workspace. R11 structure with QPB=8/TQ=32: more, smaller blocks to
// lift resident waves/CU from ~11 to ~24 (block availability was the R11 limiter).
__global__ __launch_bounds__(256, 6) void fused(const float* __restrict__ unknown,
                                                const float* __restrict__ known,
                                                const int*   __restrict__ binds,
                                                const float* __restrict__ feats,
                                                float* __restrict__ out) {
    __shared__ float2 kx2[NM / 2];  // 8 KB: {x[2p], x[2p+1]}
    __shared__ float2 ky2[NM / 2];  // 8 KB
    __shared__ float2 kz2[NM / 2];  // 8 KB
    __shared__ int qlist[QPB];
    __shared__ int wsum[4];

    const int tid  = threadIdx.x;
    const int b    = blockIdx.y;
    const int x    = blockIdx.x;
    const int lane = tid & 63;
    const int wave = tid >> 6;

    // ---- scan binds: per-thread count of batch-b points, 256-thread exclusive prefix ----
    const int4* b4 = (const int4*)binds;   // thread t owns binds[t*64 .. t*64+63]
    int myCnt = 0;
#pragma unroll
    for (int r = 0; r < 16; ++r) {
        const int4 v = b4[tid * 16 + r];
        myCnt += (v.x == b) + (v.y == b) + (v.z == b) + (v.w == b);
    }
    int inc = myCnt;
#pragma unroll
    for (int off = 1; off <= 32; off <<= 1) {
        const int n = __shfl_up(inc, off);
        if (lane >= off) inc += n;
    }
    if (lane == 63) wsum[wave] = inc;
    __syncthreads();
    int wbase = 0;
    for (int w = 0; w < wave; ++w) wbase += wsum[w];
    const int exPre = wbase + inc - myCnt;
    const int segN  = wsum[0] + wsum[1] + wsum[2] + wsum[3];

    if (x * QPB >= segN) return;           // block-uniform early exit

    // ---- stage known points of batch b into pair-SoA LDS ----
    {
        const float* kb = known + (size_t)b * NM * 3;
        for (int p = tid; p < NM / 2; p += 256) {
            const float* s = kb + p * 6;
            float2 vx, vy, vz;
            vx.x = s[0]; vy.x = s[1]; vz.x = s[2];
            vx.y = s[3]; vy.y = s[4]; vz.y = s[5];
            kx2[p] = vx; ky2[p] = vy; kz2[p] = vz;
        }
    }

    const int qi = tid >> 5;   // query within block, 0..7
    const int t  = tid & 31;   // thread within query group

    // ---- window loop (executes once since GX*QPB >= segN; mop-up kept as safety net) ----
    for (int w0 = x * QPB; w0 < segN; w0 += GX * QPB) {
        __syncthreads();       // staging complete / previous window's qlist reads done
        if (exPre < w0 + QPB && exPre + myCnt > w0) {
            int rank = exPre;
#pragma unroll
            for (int r = 0; r < 16; ++r) {
                const int4 v = b4[tid * 16 + r];
                const int base = tid * 64 + r * 4;
                if (v.x == b) { if (rank >= w0 && rank < w0 + QPB) qlist[rank - w0] = base + 0; ++rank; }
                if (v.y == b) { if (rank >= w0 && rank < w0 + QPB) qlist[rank - w0] = base + 1; ++rank; }
                if (v.z == b) { if (rank >= w0 && rank < w0 + QPB) qlist[rank - w0] = base + 2; ++rank; }
                if (v.w == b) { if (rank >= w0 && rank < w0 + QPB) qlist[rank - w0] = base + 3; ++rank; }
            }
        }
        __syncthreads();

        const int valid = (segN - w0 < QPB) ? (segN - w0) : QPB;
        const int kq    = (qi < valid) ? qi : 0;   // duplicate query -> identical bytes, benign
        const int p     = qlist[kq];
        const float ux = unknown[p * 3 + 0];
        const float uy = unknown[p * 3 + 1];
        const float uz = unknown[p * 3 + 2];

        float D0 = __builtin_inff(), D1 = __builtin_inff(), D2 = __builtin_inff();
        int   I0 = NM, I1 = NM, I2 = NM;

        // thread t handles point-pairs pr = i*32 + t  (points 2pr, 2pr+1), i = 0..31
#pragma unroll 8
        for (int i = 0; i < NM / (2 * TQ); ++i) {
            const int pr = (i << 5) | t;
            const float2 vx = kx2[pr];
            const float2 vy = ky2[pr];
            const float2 vz = kz2[pr];
            const int jLo = pr << 1;
            // strict rn, numpy association ((dx2+dy2)+dz2): selection bit-identical to ref
            const float dx0 = __fsub_rn(ux, vx.x);
            const float dy0 = __fsub_rn(uy, vy.x);
            const float dz0 = __fsub_rn(uz, vz.x);
            const float dx1 = __fsub_rn(ux, vx.y);
            const float dy1 = __fsub_rn(uy, vy.y);
            const float dz1 = __fsub_rn(uz, vz.y);
            const float dLo = __fadd_rn(__fadd_rn(__fmul_rn(dx0, dx0), __fmul_rn(dy0, dy0)),
                                        __fmul_rn(dz0, dz0));
            const float dHi = __fadd_rn(__fadd_rn(__fmul_rn(dx1, dx1), __fmul_rn(dy1, dy1)),
                                        __fmul_rn(dz1, dz1));
            MERGE3(dLo, jLo);
            MERGE3(dHi, jLo + 1);
        }

        // merge 32 partial top-3 lists (shfl_down tree within 32-lane group; lane g*32's
        // chain only aggregates in-group partials), broadcast from group base
#pragma unroll
        for (int off = 16; off >= 1; off >>= 1) {
            const float e0d = __shfl_down(D0, off);
            const float e1d = __shfl_down(D1, off);
            const float e2d = __shfl_down(D2, off);
            const int   e0i = __shfl_down(I0, off);
            const int   e1i = __shfl_down(I1, off);
            const int   e2i = __shfl_down(I2, off);
            MERGE_DI(e0d, e0i);
            MERGE_DI(e1d, e1i);
            MERGE_DI(e2d, e2i);
        }
        const int src = lane & ~31;
        D0 = __shfl(D0, src); D1 = __shfl(D1, src); D2 = __shfl(D2, src);
        I0 = __shfl(I0, src); I1 = __shfl(I1, src); I2 = __shfl(I2, src);

        const float t0 = 1.0f / (sqrtf(D0) + EPSF);
        const float t1 = 1.0f / (sqrtf(D1) + EPSF);
        const float t2 = 1.0f / (sqrtf(D2) + EPSF);
        const float s  = t0 + t1 + t2;
        const float w0w = t0 / s, w1w = t1 / s, w2w = t2 / s;

        // gather from raw (B,C,m): column reads, L2/L3-resident (feats = 8 MB)
        const float* fb = feats + (size_t)b * NC * NM;
#pragma unroll
        for (int k = 0; k < 4; ++k) {
            const int c = t + (k << 5);            // 32 lanes -> 128B-coalesced out rows
            const float* fc = fb + (size_t)c * NM;
            const float f0 = fc[I0];
            const float f1 = fc[I1];
            const float f2 = fc[I2];
            out[(size_t)p * NC + c] = w0w * f0 + w1w * f1 + w2w * f2;
        }
    }
}

extern "C" void kernel_launch(void* const* d_in, const int* in_sizes, int n_in,
                              void* d_out, int out_size, void* d_ws, size_t ws_size,
                              hipStream_t stream) {
    const float* unknown = (const float*)d_in[0];   // (n, 3)
    const float* known   = (const float*)d_in[1];   // (B, m, 3)
    const int*   binds   = (const int*)d_in[2];     // (n,)
    const float* feats   = (const float*)d_in[3];   // (B, C, m)
    float*       out     = (float*)d_out;           // (n, C, 1)

    fused<<<dim3(GX, NB), 256, 0, stream>>>(unknown, known, binds, feats, out);
}

// Round 15
// 110.654 us; speedup vs baseline: 4.9393x; 1.1228x over previous
//
#include <hip/hip_runtime.h>

#define NPTS 16384
#define NB   8
#define NM   2048
#define NC   128
#define EPSF 1e-8f

#define TQ   16                     // threads per query
#define QPB  16                     // queries per 256-thread block
#define GX   160                    // blocks per batch: 2560 slots >> segN(~2100) -> no tail

// Sorted top-3 insert via min/med3 (3 VALU for the distance regs) + 5 cndmask for
// indices (strict '<' -> earliest j kept on ties; per-thread j strictly increases).
// Equivalence verified by cases: d<D0 / D0<=d<D1 / d==D1 / D1<=d<D2 / d>=D2.
#define MERGE3(d, j) do {                                       \
    const bool _b0 = (d) < D0;                                  \
    const bool _b1 = (d) < D1;                                  \
    const bool _b2 = (d) < D2;                                  \
    const float _n0 = fminf((d), D0);                           \
    const float _n1 = __builtin_amdgcn_fmed3f(D0, D1, (d));     \
    const float _n2 = __builtin_amdgcn_fmed3f(D1, D2, (d));     \
    I2 = _b1 ? I1 : (_b2 ? (j) : I2);                           \
    I1 = _b0 ? I0 : (_b1 ? (j) : I1);                           \
    I0 = _b0 ? (j) : I0;                                        \
    D0 = _n0; D1 = _n1; D2 = _n2;                               \
} while (0)

// Cross-thread merge element: full lexicographic (d, idx) compare (once per query)
#define MERGE_DI(ed, ei) do {                                           \
    const bool _b2 = ((ed) < D2) || (((ed) == D2) && ((ei) < I2));      \
    const bool _b1 = ((ed) < D1) || (((ed) == D1) && ((ei) < I1));      \
    const bool _b0 = ((ed) < D0) || (((ed) == D0) && ((ei) < I0));      \
    D2 = _b1 ? D1 : (_b2 ? (ed) : D2);                                  \
    I2 = _b1 ? I1 : (_b2 ? (ei) : I2);                                  \
    D1 = _b0 ? D0 : (_b1 ? (ed) : D1);                                  \
    I1 = _b0 ? I0 : (_b1 ? (ei) : I1);                                  \
    D0 = _b0 ? (ed) : D0;                                               \
    I0 = _b0 ? (ei) : I0;                                               \
} while (0)

// ONE dispatch, no workspace (best measured variant: R11 — 2 points/iter, float2 SoA LDS,
// min/med3 merge, QPB=16, GX=160).
__global__ __launch_bounds__(256, 4) void fused(const float* __restrict__ unknown,
                                                const float* __restrict__ known,
                                                const int*   __restrict__ binds,
                                                const float* __restrict__ feats,
                                                float* __restrict__ out) {
    __shared__ float2 kx2[NM / 2];  // 8 KB: {x[2p], x[2p+1]}
    __shared__ float2 ky2[NM / 2];  // 8 KB
    __shared__ float2 kz2[NM / 2];  // 8 KB
    __shared__ int qlist[QPB];
    __shared__ int wsum[4];

    const int tid  = threadIdx.x;
    const int b    = blockIdx.y;
    const int x    = blockIdx.x;
    const int lane = tid & 63;
    const int wave = tid >> 6;

    // ---- scan binds: per-thread count of batch-b points, 256-thread exclusive prefix ----
    const int4* b4 = (const int4*)binds;   // thread t owns binds[t*64 .. t*64+63]
    int myCnt = 0;
#pragma unroll
    for (int r = 0; r < 16; ++r) {
        const int4 v = b4[tid * 16 + r];
        myCnt += (v.x == b) + (v.y == b) + (v.z == b) + (v.w == b);
    }
    int inc = myCnt;
#pragma unroll
    for (int off = 1; off <= 32; off <<= 1) {
        const int n = __shfl_up(inc, off);
        if (lane >= off) inc += n;
    }
    if (lane == 63) wsum[wave] = inc;
    __syncthreads();
    int wbase = 0;
    for (int w = 0; w < wave; ++w) wbase += wsum[w];
    const int exPre = wbase + inc - myCnt;
    const int segN  = wsum[0] + wsum[1] + wsum[2] + wsum[3];

    if (x * QPB >= segN) return;           // block-uniform early exit

    // ---- stage known points of batch b into pair-SoA LDS ----
    {
        const float* kb = known + (size_t)b * NM * 3;
        for (int p = tid; p < NM / 2; p += 256) {
            const float* s = kb + p * 6;
            float2 vx, vy, vz;
            vx.x = s[0]; vy.x = s[1]; vz.x = s[2];
            vx.y = s[3]; vy.y = s[4]; vz.y = s[5];
            kx2[p] = vx; ky2[p] = vy; kz2[p] = vz;
        }
    }

    const int qi = tid >> 4;   // query within block, 0..15
    const int t  = tid & 15;   // thread within query group

    // ---- window loop (executes once since GX*QPB >= segN; mop-up kept as safety net) ----
    for (int w0 = x * QPB; w0 < segN; w0 += GX * QPB) {
        __syncthreads();       // staging complete / previous window's qlist reads done
        if (exPre < w0 + QPB && exPre + myCnt > w0) {
            int rank = exPre;
#pragma unroll
            for (int r = 0; r < 16; ++r) {
                const int4 v = b4[tid * 16 + r];
                const int base = tid * 64 + r * 4;
                if (v.x == b) { if (rank >= w0 && rank < w0 + QPB) qlist[rank - w0] = base + 0; ++rank; }
                if (v.y == b) { if (rank >= w0 && rank < w0 + QPB) qlist[rank - w0] = base + 1; ++rank; }
                if (v.z == b) { if (rank >= w0 && rank < w0 + QPB) qlist[rank - w0] = base + 2; ++rank; }
                if (v.w == b) { if (rank >= w0 && rank < w0 + QPB) qlist[rank - w0] = base + 3; ++rank; }
            }
        }
        __syncthreads();

        const int valid = (segN - w0 < QPB) ? (segN - w0) : QPB;
        const int kq    = (qi < valid) ? qi : 0;   // duplicate query -> identical bytes, benign
        const int p     = qlist[kq];
        const float ux = unknown[p * 3 + 0];
        const float uy = unknown[p * 3 + 1];
        const float uz = unknown[p * 3 + 2];

        float D0 = __builtin_inff(), D1 = __builtin_inff(), D2 = __builtin_inff();
        int   I0 = NM, I1 = NM, I2 = NM;

        // thread t handles point-pairs pr = i*16 + t  (points 2pr, 2pr+1), i = 0..63
#pragma unroll 8
        for (int i = 0; i < NM / (2 * TQ); ++i) {
            const int pr = (i << 4) | t;
            const float2 vx = kx2[pr];
            const float2 vy = ky2[pr];
            const float2 vz = kz2[pr];
            const int jLo = pr << 1;
            // strict rn, numpy association ((dx2+dy2)+dz2): selection bit-identical to ref
            const float dx0 = __fsub_rn(ux, vx.x);
            const float dy0 = __fsub_rn(uy, vy.x);
            const float dz0 = __fsub_rn(uz, vz.x);
            const float dx1 = __fsub_rn(ux, vx.y);
            const float dy1 = __fsub_rn(uy, vy.y);
            const float dz1 = __fsub_rn(uz, vz.y);
            const float dLo = __fadd_rn(__fadd_rn(__fmul_rn(dx0, dx0), __fmul_rn(dy0, dy0)),
                                        __fmul_rn(dz0, dz0));
            const float dHi = __fadd_rn(__fadd_rn(__fmul_rn(dx1, dx1), __fmul_rn(dy1, dy1)),
                                        __fmul_rn(dz1, dz1));
            MERGE3(dLo, jLo);
            MERGE3(dHi, jLo + 1);
        }

        // merge 16 partial top-3 lists (shfl_down tree; valid at group lane 0), broadcast
#pragma unroll
        for (int off = 8; off >= 1; off >>= 1) {
            const float e0d = __shfl_down(D0, off);
            const float e1d = __shfl_down(D1, off);
            const float e2d = __shfl_down(D2, off);
            const int   e0i = __shfl_down(I0, off);
            const int   e1i = __shfl_down(I1, off);
            const int   e2i = __shfl_down(I2, off);
            MERGE_DI(e0d, e0i);
            MERGE_DI(e1d, e1i);
            MERGE_DI(e2d, e2i);
        }
        const int src = lane & ~15;
        D0 = __shfl(D0, src); D1 = __shfl(D1, src); D2 = __shfl(D2, src);
        I0 = __shfl(I0, src); I1 = __shfl(I1, src); I2 = __shfl(I2, src);

        const float t0 = 1.0f / (sqrtf(D0) + EPSF);
        const float t1 = 1.0f / (sqrtf(D1) + EPSF);
        const float t2 = 1.0f / (sqrtf(D2) + EPSF);
        const float s  = t0 + t1 + t2;
        const float w0w = t0 / s, w1w = t1 / s, w2w = t2 / s;

        // gather from raw (B,C,m): column reads, L2/L3-resident (feats = 8 MB)
        const float* fb = feats + (size_t)b * NC * NM;
#pragma unroll
        for (int k = 0; k < 8; ++k) {
            const int c = t + (k << 4);            // 16 lanes -> 64B-coalesced out rows
            const float* fc = fb + (size_t)c * NM;
            const float f0 = fc[I0];
            const float f1 = fc[I1];
            const float f2 = fc[I2];
            out[(size_t)p * NC + c] = w0w * f0 + w1w * f1 + w2w * f2;
        }
    }
}

extern "C" void kernel_launch(void* const* d_in, const int* in_sizes, int n_in,
                              void* d_out, int out_size, void* d_ws, size_t ws_size,
                              hipStream_t stream) {
    const float* unknown = (const float*)d_in[0];   // (n, 3)
    const float* known   = (const float*)d_in[1];   // (B, m, 3)
    const int*   binds   = (const int*)d_in[2];     // (n,)
    const float* feats   = (const float*)d_in[3];   // (B, C, m)
    float*       out     = (float*)d_out;           // (n, C, 1)

    fused<<<dim3(GX, NB), 256, 0, stream>>>(unknown, known, binds, feats, out);
}